// Round 1
// baseline (110.786 us; speedup 1.0000x reference)
//
#include <hip/hip_runtime.h>

// CorrelationLayer: out[1,49,H,W], out[j*7+i,h,w] = sum_c x[c,h,w]*y[c,h+j-3,w+i-3]
// B=1, C=128, H=384, W=512, zero padding outside y.
//
// Strategy: block = 7 waves = one output row h. Wave j handles displacement
// row j (all 7 i). Lane covers 8 consecutive w (64 lanes * 8 = 512 = W).
// 56 fp32 accumulators/lane. No LDS, no barriers. Zero-pad in w via clamped
// edge loads + cndmask zeroing of the 3 boundary window slots. Rows outside
// y (r<0 or r>=H) contribute zeros (acc stays 0, loop skipped, zeros stored).
// XCD-contiguous block swizzle keeps the 7-row y reuse window in one XCD L2.

constexpr int C = 128;
constexpr int H = 384;
constexpr int W = 512;
constexpr int HW = H * W;

__global__ __launch_bounds__(448)
void corr_kernel(const float* __restrict__ x,
                 const float* __restrict__ y,
                 float* __restrict__ out) {
  const int bid  = blockIdx.x;
  // 384 blocks = 8 XCDs * 48 rows; round-robin dispatch -> XCD k gets rows [48k,48k+48)
  const int h    = (bid & 7) * 48 + (bid >> 3);
  const int j    = threadIdx.x >> 6;   // 0..6, displacement row
  const int lane = threadIdx.x & 63;
  const int r    = h + j - 3;          // y row for this wave

  float acc[7][8];
#pragma unroll
  for (int i = 0; i < 7; ++i)
#pragma unroll
    for (int p = 0; p < 8; ++p) acc[i][p] = 0.f;

  const int w0 = lane * 8;             // first output pixel of this lane

  if (r >= 0 && r < H) {
    // window covers y[r, w0-4 .. w0+11]; used entries are w0-3 .. w0+10
    int o0 = w0 - 4;
    int o3 = w0 + 8;
    if (o0 < 0) o0 = 0;                // lane 0: garbage, zeroed below
    if (o3 > W - 4) o3 = W - 4;        // lane 63: garbage, zeroed below
    const int o1 = w0;
    const int o2 = w0 + 4;
    const bool lo = (lane == 0);
    const bool hi = (lane == 63);

    const float* xp = x + (size_t)h * W + w0;
    const float* yp = y + (size_t)r * W;

#pragma unroll 2
    for (int c = 0; c < C; ++c) {
      const float4 xv0 = *reinterpret_cast<const float4*>(xp);
      const float4 xv1 = *reinterpret_cast<const float4*>(xp + 4);
      const float4 y0  = *reinterpret_cast<const float4*>(yp + o0);
      const float4 y1  = *reinterpret_cast<const float4*>(yp + o1);
      const float4 y2  = *reinterpret_cast<const float4*>(yp + o2);
      const float4 y3  = *reinterpret_cast<const float4*>(yp + o3);
      xp += HW;
      yp += HW;

      float wq[16];
      wq[0]  = y0.x; wq[1]  = y0.y; wq[2]  = y0.z; wq[3]  = y0.w;
      wq[4]  = y1.x; wq[5]  = y1.y; wq[6]  = y1.z; wq[7]  = y1.w;
      wq[8]  = y2.x; wq[9]  = y2.y; wq[10] = y2.z; wq[11] = y2.w;
      wq[12] = y3.x; wq[13] = y3.y; wq[14] = y3.z; wq[15] = y3.w;
      // zero-padding fixups: lane 0 window slots 1..3 are y[-3..-1];
      // lane 63 slots 12..14 are y[512..514]
      wq[1]  = lo ? 0.f : wq[1];
      wq[2]  = lo ? 0.f : wq[2];
      wq[3]  = lo ? 0.f : wq[3];
      wq[12] = hi ? 0.f : wq[12];
      wq[13] = hi ? 0.f : wq[13];
      wq[14] = hi ? 0.f : wq[14];

      const float xs[8] = {xv0.x, xv0.y, xv0.z, xv0.w,
                           xv1.x, xv1.y, xv1.z, xv1.w};
      // out pixel w0+p, disp i: needs y[w0+p+i-3] = wq[p+i+1]
#pragma unroll
      for (int i = 0; i < 7; ++i)
#pragma unroll
        for (int p = 0; p < 8; ++p)
          acc[i][p] = fmaf(xs[p], wq[p + i + 1], acc[i][p]);
    }
  }

#pragma unroll
  for (int i = 0; i < 7; ++i) {
    float* o = out + (size_t)(j * 7 + i) * HW + (size_t)h * W + w0;
    float4 a = make_float4(acc[i][0], acc[i][1], acc[i][2], acc[i][3]);
    float4 b = make_float4(acc[i][4], acc[i][5], acc[i][6], acc[i][7]);
    *reinterpret_cast<float4*>(o)     = a;
    *reinterpret_cast<float4*>(o + 4) = b;
  }
}

extern "C" void kernel_launch(void* const* d_in, const int* in_sizes, int n_in,
                              void* d_out, int out_size, void* d_ws, size_t ws_size,
                              hipStream_t stream) {
  const float* x = (const float*)d_in[0];
  const float* y = (const float*)d_in[1];
  float* out = (float*)d_out;
  corr_kernel<<<dim3(H), dim3(448), 0, stream>>>(x, y, out);
}

// Round 2
// 95.127 us; speedup vs baseline: 1.1646x; 1.1646x over previous
//
#include <hip/hip_runtime.h>

// CorrelationLayer: out[1,49,H,W], out[j*7+i,h,w] = sum_c x[c,h,w]*y[c,h+j-3,w+i-3]
// B=1, C=128, H=384, W=512, zero padding outside y.
//
// R2: block = 7 waves = one output HALF-row (256 px). Wave j handles
// displacement row j (all 7 i). Lane covers 4 consecutive w (64*4 = 256).
// Grid = 384 rows * 2 segments = 768 blocks = 5376 waves = 5.25 waves/SIMD
// (R1 was 2.6 waves/SIMD -> latency-bound at 18% VALUBusy).
// 28 fp32 accumulators/lane, no LDS, no barriers. Zero-pad in w via clamped
// edge loads + cndmask zeroing of boundary window slots. Rows outside y
// contribute zeros. XCD-contiguous swizzle: XCD k owns rows [48k,48k+48).

constexpr int C = 128;
constexpr int H = 384;
constexpr int W = 512;
constexpr int HW = H * W;

__global__ __launch_bounds__(448)
void corr_kernel(const float* __restrict__ x,
                 const float* __restrict__ y,
                 float* __restrict__ out) {
  const int bid  = blockIdx.x;
  const int idx  = bid >> 3;              // 0..95 within XCD
  const int h    = (bid & 7) * 48 + (idx >> 1);
  const int wbase = (idx & 1) * 256;      // half-row segment
  const int j    = threadIdx.x >> 6;      // 0..6, displacement row
  const int lane = threadIdx.x & 63;
  const int r    = h + j - 3;             // y row for this wave

  float acc[7][4];
#pragma unroll
  for (int i = 0; i < 7; ++i)
#pragma unroll
    for (int p = 0; p < 4; ++p) acc[i][p] = 0.f;

  const int w0 = wbase + lane * 4;        // first output pixel of this lane

  if (r >= 0 && r < H) {
    // window wq[0..11] = y[r, w0-4 .. w0+7]; used entries are w0-3 .. w0+6
    int o0 = w0 - 4;
    int o2 = w0 + 4;
    if (o0 < 0) o0 = 0;                   // w0==0: slots 1..3 garbage, zeroed
    if (o2 > W - 4) o2 = W - 4;           // w0==508: slots 8..10 garbage, zeroed
    const int o1 = w0;
    const bool lo = (w0 == 0);
    const bool hi = (w0 == W - 4);

    const float* xp = x + (size_t)h * W + w0;
    const float* yp = y + (size_t)r * W;

#pragma unroll 2
    for (int c = 0; c < C; ++c) {
      const float4 xv = *reinterpret_cast<const float4*>(xp);
      const float4 y0 = *reinterpret_cast<const float4*>(yp + o0);
      const float4 y1 = *reinterpret_cast<const float4*>(yp + o1);
      const float4 y2 = *reinterpret_cast<const float4*>(yp + o2);
      xp += HW;
      yp += HW;

      float wq[12];
      wq[0]  = y0.x; wq[1]  = y0.y; wq[2]  = y0.z; wq[3]  = y0.w;
      wq[4]  = y1.x; wq[5]  = y1.y; wq[6]  = y1.z; wq[7]  = y1.w;
      wq[8]  = y2.x; wq[9]  = y2.y; wq[10] = y2.z; wq[11] = y2.w;
      // zero-padding fixups at the absolute row edges
      wq[1]  = lo ? 0.f : wq[1];
      wq[2]  = lo ? 0.f : wq[2];
      wq[3]  = lo ? 0.f : wq[3];
      wq[8]  = hi ? 0.f : wq[8];
      wq[9]  = hi ? 0.f : wq[9];
      wq[10] = hi ? 0.f : wq[10];

      const float xs[4] = {xv.x, xv.y, xv.z, xv.w};
      // out pixel w0+p, disp i: needs y[w0+p+i-3] = wq[p+i+1]
#pragma unroll
      for (int i = 0; i < 7; ++i)
#pragma unroll
        for (int p = 0; p < 4; ++p)
          acc[i][p] = fmaf(xs[p], wq[p + i + 1], acc[i][p]);
    }
  }

#pragma unroll
  for (int i = 0; i < 7; ++i) {
    float* o = out + (size_t)(j * 7 + i) * HW + (size_t)h * W + w0;
    *reinterpret_cast<float4*>(o) =
        make_float4(acc[i][0], acc[i][1], acc[i][2], acc[i][3]);
  }
}

extern "C" void kernel_launch(void* const* d_in, const int* in_sizes, int n_in,
                              void* d_out, int out_size, void* d_ws, size_t ws_size,
                              hipStream_t stream) {
  const float* x = (const float*)d_in[0];
  const float* y = (const float*)d_in[1];
  float* out = (float*)d_out;
  corr_kernel<<<dim3(H * 2), dim3(448), 0, stream>>>(x, y, out);
}

// Round 4
// 90.152 us; speedup vs baseline: 1.2289x; 1.0552x over previous
//
#include <hip/hip_runtime.h>

// CorrelationLayer: out[1,49,H,W], out[j*7+i,h,w] = sum_c x[c,h,w]*y[c,h+j-3,w+i-3]
// B=1, C=128, H=384, W=512, zero padding outside y.
//
// R4 = R3 with the bpermute-in-ternary bug fixed: all ds_bpermute calls are
// executed unconditionally (full exec mask) as standalone statements; edge
// lanes then SELECT between the bpermute result and their edge-load registers.
// (R3 put bpermute inside a ternary arm -> frontend branch -> convergent op
// ran with lanes 0/63 masked off -> neighbors pulled from disabled lanes.)
//
// Geometry: block = 7 waves = one output half-row (256 px), wave j = disp row,
// lane = 4 px, grid = 768. Loads per lane per channel: 2 (own y, own x)
// + 1 exec-masked edge load on one lane/wave. Halo via 6 bpermutes/channel.

constexpr int C = 128;
constexpr int H = 384;
constexpr int W = 512;
constexpr int HW = H * W;

__device__ __forceinline__ float bperm(int addr, float v) {
  return __int_as_float(__builtin_amdgcn_ds_bpermute(addr, __float_as_int(v)));
}

__global__ __launch_bounds__(448, 6)
void corr_kernel(const float* __restrict__ x,
                 const float* __restrict__ y,
                 float* __restrict__ out) {
  const int bid   = blockIdx.x;
  const int idx   = bid >> 3;             // 0..95 within XCD
  const int h     = (bid & 7) * 48 + (idx >> 1);
  const int seg   = idx & 1;
  const int wbase = seg * 256;            // half-row segment
  const int j     = threadIdx.x >> 6;     // 0..6, displacement row
  const int lane  = threadIdx.x & 63;
  const int r     = h + j - 3;            // y row for this wave

  float acc[7][4];
#pragma unroll
  for (int i = 0; i < 7; ++i)
#pragma unroll
    for (int p = 0; p < 4; ++p) acc[i][p] = 0.f;

  const int w0 = wbase + lane * 4;        // first output pixel of this lane

  if (r >= 0 && r < H) {
    const int upA = ((lane - 1) & 63) << 2;   // bpermute byte addr: lane-1
    const int dnA = ((lane + 1) & 63) << 2;   // lane+1
    const bool lo = (lane == 0);
    const bool hi = (lane == 63);
    // lanes 0/63 need halo data from outside the wave's 256-px span:
    //   lane 0 : y[w0-4..w0-1]  (exists iff seg==1; seg==0 -> zeros)
    //   lane 63: y[w0+4..w0+7]  (exists iff seg==0; seg==1 -> zeros)
    const bool eload = (lo && seg == 1) || (hi && seg == 0);
    int eoff = lo ? (w0 - 4) : (w0 + 4);
    if (eoff < 0) eoff = 0;
    if (eoff > W - 4) eoff = W - 4;       // keep address sane when masked off

    const float* xp = x + (size_t)h * W + w0;
    const float* yp = y + (size_t)r * W + w0;
    const float* ep = y + (size_t)r * W + eoff;

#pragma unroll 1
    for (int c = 0; c < C; c += 2) {
      // grouped loads for MLP (unroll 2)
      const float4 yv0 = *reinterpret_cast<const float4*>(yp);
      const float4 xv0 = *reinterpret_cast<const float4*>(xp);
      const float4 yv1 = *reinterpret_cast<const float4*>(yp + HW);
      const float4 xv1 = *reinterpret_cast<const float4*>(xp + HW);
      float4 ev0 = make_float4(0.f, 0.f, 0.f, 0.f);
      float4 ev1 = make_float4(0.f, 0.f, 0.f, 0.f);
      if (eload) {
        ev0 = *reinterpret_cast<const float4*>(ep);
        ev1 = *reinterpret_cast<const float4*>(ep + HW);
      }
      yp += 2 * HW; xp += 2 * HW; ep += 2 * HW;

#pragma unroll
      for (int u = 0; u < 2; ++u) {
        const float4 yv = u ? yv1 : yv0;
        const float4 xv = u ? xv1 : xv0;
        const float4 ev = u ? ev1 : ev0;

        // Unconditional cross-lane pulls (full exec mask — do NOT put these
        // inside ternaries/branches; convergent op + masked source lane = UB).
        const float hl1 = bperm(upA, yv.y);   // y[w0-3] for lanes 1..63
        const float hl2 = bperm(upA, yv.z);   // y[w0-2]
        const float hl3 = bperm(upA, yv.w);   // y[w0-1]
        const float hr0 = bperm(dnA, yv.x);   // y[w0+4] for lanes 0..62
        const float hr1 = bperm(dnA, yv.y);   // y[w0+5]
        const float hr2 = bperm(dnA, yv.z);   // y[w0+6]

        // window wq[1..10] = y[r, w0-3 .. w0+6]
        float wq[12];
        wq[1]  = lo ? ev.y : hl1;
        wq[2]  = lo ? ev.z : hl2;
        wq[3]  = lo ? ev.w : hl3;
        wq[4]  = yv.x; wq[5] = yv.y; wq[6] = yv.z; wq[7] = yv.w;
        wq[8]  = hi ? ev.x : hr0;
        wq[9]  = hi ? ev.y : hr1;
        wq[10] = hi ? ev.z : hr2;

        const float xs[4] = {xv.x, xv.y, xv.z, xv.w};
        // out pixel w0+p, disp i: needs y[w0+p+i-3] = wq[p+i+1]
#pragma unroll
        for (int i = 0; i < 7; ++i)
#pragma unroll
          for (int p = 0; p < 4; ++p)
            acc[i][p] = fmaf(xs[p], wq[p + i + 1], acc[i][p]);
      }
    }
  }

#pragma unroll
  for (int i = 0; i < 7; ++i) {
    float* o = out + (size_t)(j * 7 + i) * HW + (size_t)h * W + w0;
    *reinterpret_cast<float4*>(o) =
        make_float4(acc[i][0], acc[i][1], acc[i][2], acc[i][3]);
  }
}

extern "C" void kernel_launch(void* const* d_in, const int* in_sizes, int n_in,
                              void* d_out, int out_size, void* d_ws, size_t ws_size,
                              hipStream_t stream) {
  const float* x = (const float*)d_in[0];
  const float* y = (const float*)d_in[1];
  float* out = (float*)d_out;
  corr_kernel<<<dim3(H * 2), dim3(448), 0, stream>>>(x, y, out);
}